// Round 9
// baseline (1871.628 us; speedup 1.0000x reference)
//
#include <hip/hip_runtime.h>
#include <hip/hip_bf16.h>
#include <stdint.h>

typedef __attribute__((ext_vector_type(8))) short short8;
typedef __attribute__((ext_vector_type(4))) float f32x4;

#define N_NODES 16384
#define D_IN    512
#define D_HID   256
#define D_OUT   64
#define S_SAMP  4096

__device__ __forceinline__ unsigned short f2bf(float f) {
  __hip_bfloat16 h = __float2bfloat16(f);
  union { __hip_bfloat16 h; unsigned short u; } cv; cv.h = h; return cv.u;
}

// ---------------------------------------------------------------------------
// gemm_tn — R2 baseline (single-buffered As/Bs, BK=64, two barriers/K-step).
// ---------------------------------------------------------------------------
template<int BM, int BN, int BK, bool RELU_A>
__global__ __launch_bounds__(256)
void gemm_tn(const float* __restrict__ A, int lda,
             const int* __restrict__ arow,
             const unsigned short* __restrict__ Bt, int ldb,
             float* __restrict__ C, int ldc,
             int K, int kChunks, float scale)
{
  static_assert(BM == 64 && BK == 64 && (BN == 64 || BN == 256), "tile");
  constexpr int CH    = BK / 8;
  constexpr int RPS   = 512 / BK;
  constexpr int SLABS = BN / RPS;
  constexpr int SLABW = SLABS / 4;

  const int mt  = blockIdx.x / kChunks;
  const int kc  = blockIdx.x % kChunks;
  const int kLen = K / kChunks;
  const int k0   = kc * kLen;
  const int tid  = threadIdx.x;
  const int lane = tid & 63;
  const int wid  = tid >> 6;
  const int l16  = lane & 15;
  const int lg   = lane >> 4;

  __shared__ unsigned short As[BM * BK];
  __shared__ unsigned short Bs[BN * BK];

  constexpr int WN  = (BN == 256) ? 4 : 2;
  constexpr int WM  = 4 / WN;
  constexpr int WTM = BM / WM;
  constexpr int WTN = BN / WN;
  constexpr int MF  = WTM / 16;
  constexpr int NF  = WTN / 16;
  const int wrow = wid / WN;
  const int wcol = wid % WN;

  f32x4 acc[MF][NF] = {};

  const int am   = tid >> 2;
  const int aseg = tid & 3;
  const int arowIdx = mt * BM + am;
  const size_t rowg = arow ? (size_t)arow[arowIdx] : (size_t)arowIdx;
  const float* aBase = A + rowg * (size_t)lda + k0 + aseg * 16;

  const int brow = lane / CH;
  const int bcol = 8 * ((lane % CH) ^ (brow & (CH - 1)));
  const unsigned short* bSrc = Bt + (size_t)brow * ldb + k0 + bcol;

  for (int ks = 0; ks < kLen; ks += BK) {
    __syncthreads();
    #pragma unroll
    for (int i = 0; i < SLABW; ++i) {
      const int s = wid * SLABW + i;
      __builtin_amdgcn_global_load_lds(
          (const __attribute__((address_space(1))) uint32_t*)(bSrc + (size_t)s * RPS * ldb + ks),
          (__attribute__((address_space(3))) uint32_t*)(&Bs[s * 512]),
          16, 0, 0);
    }
    {
      const float* ap = aBase + ks;
      f32x4 v0 = *(const f32x4*)(ap + 0);
      f32x4 v1 = *(const f32x4*)(ap + 4);
      f32x4 v2 = *(const f32x4*)(ap + 8);
      f32x4 v3 = *(const f32x4*)(ap + 12);
      if (RELU_A) {
        #pragma unroll
        for (int j = 0; j < 4; ++j) {
          v0[j] = fmaxf(v0[j], 0.f); v1[j] = fmaxf(v1[j], 0.f);
          v2[j] = fmaxf(v2[j], 0.f); v3[j] = fmaxf(v3[j], 0.f);
        }
      }
      short8 s0, s1;
      s0[0]=f2bf(v0[0]); s0[1]=f2bf(v0[1]); s0[2]=f2bf(v0[2]); s0[3]=f2bf(v0[3]);
      s0[4]=f2bf(v1[0]); s0[5]=f2bf(v1[1]); s0[6]=f2bf(v1[2]); s0[7]=f2bf(v1[3]);
      s1[0]=f2bf(v2[0]); s1[1]=f2bf(v2[1]); s1[2]=f2bf(v2[2]); s1[3]=f2bf(v2[3]);
      s1[4]=f2bf(v3[0]); s1[5]=f2bf(v3[1]); s1[6]=f2bf(v3[2]); s1[7]=f2bf(v3[3]);
      const int g0 = (aseg * 2)     ^ (am & 7);
      const int g1 = (aseg * 2 + 1) ^ (am & 7);
      *(short8*)&As[am * BK + g0 * 8] = s0;
      *(short8*)&As[am * BK + g1 * 8] = s1;
    }
    __syncthreads();
    #pragma unroll
    for (int kk = 0; kk < BK / 32; ++kk) {
      const int gk = kk * 4 + lg;
      short8 af[MF], bfr[NF];
      #pragma unroll
      for (int fm = 0; fm < MF; ++fm) {
        const int m = wrow * WTM + fm * 16 + l16;
        af[fm] = *(const short8*)&As[m * BK + ((gk ^ (m & 7)) * 8)];
      }
      #pragma unroll
      for (int fn = 0; fn < NF; ++fn) {
        const int n = wcol * WTN + fn * 16 + l16;
        bfr[fn] = *(const short8*)&Bs[n * BK + ((gk ^ (n & 7)) * 8)];
      }
      #pragma unroll
      for (int fm = 0; fm < MF; ++fm)
        #pragma unroll
        for (int fn = 0; fn < NF; ++fn)
          acc[fm][fn] = __builtin_amdgcn_mfma_f32_16x16x32_bf16(
              af[fm], bfr[fn], acc[fm][fn], 0, 0, 0);
    }
  }
  #pragma unroll
  for (int fm = 0; fm < MF; ++fm)
    #pragma unroll
    for (int fn = 0; fn < NF; ++fn)
      #pragma unroll
      for (int j = 0; j < 4; ++j) {
        const int r = mt * BM + wrow * WTM + fm * 16 + lg * 4 + j;
        const int c = wcol * WTN + fn * 16 + l16;
        atomicAdd(&C[(size_t)r * ldc + c], scale * acc[fm][fn][j]);
      }
}

// ---------------------------------------------------------------------------
// gemm_probe — DIAGNOSTIC ONLY. Verbatim gemm_tn body wrapped in a runtime
// rep-loop so one dispatch runs reps x the real kernel and cracks the rocprof
// top-5 (which is otherwise filled by ~650us harness poison-fills), exposing
// per-kernel PMC. Output goes to dead scratch; d_out is never touched.
// ---------------------------------------------------------------------------
template<int BM, int BN, int BK>
__global__ __launch_bounds__(256)
void gemm_probe(const float* __restrict__ A, int lda,
                const int* __restrict__ arow,
                const unsigned short* __restrict__ Bt, int ldb,
                float* __restrict__ C, int ldc,
                int K, int kChunks, float scale, int reps)
{
  static_assert(BM == 64 && BK == 64 && (BN == 64 || BN == 256), "tile");
  constexpr int CH    = BK / 8;
  constexpr int RPS   = 512 / BK;
  constexpr int SLABS = BN / RPS;
  constexpr int SLABW = SLABS / 4;

  const int mt  = blockIdx.x / kChunks;
  const int kc  = blockIdx.x % kChunks;
  const int kLen = K / kChunks;
  const int k0   = kc * kLen;
  const int tid  = threadIdx.x;
  const int lane = tid & 63;
  const int wid  = tid >> 6;
  const int l16  = lane & 15;
  const int lg   = lane >> 4;

  __shared__ unsigned short As[BM * BK];
  __shared__ unsigned short Bs[BN * BK];

  constexpr int WN  = (BN == 256) ? 4 : 2;
  constexpr int WM  = 4 / WN;
  constexpr int WTM = BM / WM;
  constexpr int WTN = BN / WN;
  constexpr int MF  = WTM / 16;
  constexpr int NF  = WTN / 16;
  const int wrow = wid / WN;
  const int wcol = wid % WN;

  f32x4 acc[MF][NF] = {};

  const int am   = tid >> 2;
  const int aseg = tid & 3;
  const int arowIdx = mt * BM + am;
  const size_t rowg = arow ? (size_t)arow[arowIdx] : (size_t)arowIdx;
  const float* aBase = A + rowg * (size_t)lda + k0 + aseg * 16;

  const int brow = lane / CH;
  const int bcol = 8 * ((lane % CH) ^ (brow & (CH - 1)));
  const unsigned short* bSrc = Bt + (size_t)brow * ldb + k0 + bcol;

  for (int rep = 0; rep < reps; ++rep) {
    for (int ks = 0; ks < kLen; ks += BK) {
      __syncthreads();
      #pragma unroll
      for (int i = 0; i < SLABW; ++i) {
        const int s = wid * SLABW + i;
        __builtin_amdgcn_global_load_lds(
            (const __attribute__((address_space(1))) uint32_t*)(bSrc + (size_t)s * RPS * ldb + ks),
            (__attribute__((address_space(3))) uint32_t*)(&Bs[s * 512]),
            16, 0, 0);
      }
      {
        const float* ap = aBase + ks;
        f32x4 v0 = *(const f32x4*)(ap + 0);
        f32x4 v1 = *(const f32x4*)(ap + 4);
        f32x4 v2 = *(const f32x4*)(ap + 8);
        f32x4 v3 = *(const f32x4*)(ap + 12);
        short8 s0, s1;
        s0[0]=f2bf(v0[0]); s0[1]=f2bf(v0[1]); s0[2]=f2bf(v0[2]); s0[3]=f2bf(v0[3]);
        s0[4]=f2bf(v1[0]); s0[5]=f2bf(v1[1]); s0[6]=f2bf(v1[2]); s0[7]=f2bf(v1[3]);
        s1[0]=f2bf(v2[0]); s1[1]=f2bf(v2[1]); s1[2]=f2bf(v2[2]); s1[3]=f2bf(v2[3]);
        s1[4]=f2bf(v3[0]); s1[5]=f2bf(v3[1]); s1[6]=f2bf(v3[2]); s1[7]=f2bf(v3[3]);
        const int g0 = (aseg * 2)     ^ (am & 7);
        const int g1 = (aseg * 2 + 1) ^ (am & 7);
        *(short8*)&As[am * BK + g0 * 8] = s0;
        *(short8*)&As[am * BK + g1 * 8] = s1;
      }
      __syncthreads();
      #pragma unroll
      for (int kk = 0; kk < BK / 32; ++kk) {
        const int gk = kk * 4 + lg;
        short8 af[MF], bfr[NF];
        #pragma unroll
        for (int fm = 0; fm < MF; ++fm) {
          const int m = wrow * WTM + fm * 16 + l16;
          af[fm] = *(const short8*)&As[m * BK + ((gk ^ (m & 7)) * 8)];
        }
        #pragma unroll
        for (int fn = 0; fn < NF; ++fn) {
          const int n = wcol * WTN + fn * 16 + l16;
          bfr[fn] = *(const short8*)&Bs[n * BK + ((gk ^ (n & 7)) * 8)];
        }
        #pragma unroll
        for (int fm = 0; fm < MF; ++fm)
          #pragma unroll
          for (int fn = 0; fn < NF; ++fn)
            acc[fm][fn] = __builtin_amdgcn_mfma_f32_16x16x32_bf16(
                af[fm], bfr[fn], acc[fm][fn], 0, 0, 0);
      }
    }
    #pragma unroll
    for (int fm = 0; fm < MF; ++fm)
      #pragma unroll
      for (int fn = 0; fn < NF; ++fn)
        #pragma unroll
        for (int j = 0; j < 4; ++j) {
          const int r = mt * BM + wrow * WTM + fm * 16 + lg * 4 + j;
          const int c = wcol * WTN + fn * 16 + l16;
          atomicAdd(&C[(size_t)r * ldc + c], scale * acc[fm][fn][j]);
        }
  }
}

// transpose-convert weights: W1t[j][i] = bf16(W1[i][j]), W2t likewise
__global__ void conv_w_t(const float* __restrict__ W1, const float* __restrict__ W2,
                         unsigned short* __restrict__ W1t, unsigned short* __restrict__ W2t) {
  const int idx = blockIdx.x * 256 + threadIdx.x;
  if (idx < D_IN * D_HID) {
    const int j = idx / D_IN, i = idx % D_IN;
    W1t[idx] = f2bf(W1[(size_t)i * D_HID + j]);
  }
  if (idx < D_HID * D_OUT) {
    const int j = idx / D_HID, i = idx % D_HID;
    W2t[idx] = f2bf(W2[(size_t)i * D_OUT + j]);
  }
}

// BextT[c][rows[r]] = bf16(relu(G[r][c] + bias[c]))   (BextT pre-zeroed)
__global__ void ep_scatter_t(const float* __restrict__ G, const float* __restrict__ bias,
                             const int* __restrict__ rows, unsigned short* __restrict__ BextT,
                             int ncol, int total) {
  const int idx = blockIdx.x * 256 + threadIdx.x;
  if (idx >= total) return;
  const int c = idx / S_SAMP;
  const int r = idx & (S_SAMP - 1);
  float v = G[(size_t)r * ncol + c] + bias[c];
  v = v > 0.f ? v : 0.f;
  BextT[(size_t)c * N_NODES + rows[r]] = f2bf(v);
}

extern "C" void kernel_launch(void* const* d_in, const int* in_sizes, int n_in,
                              void* d_out, int out_size, void* d_ws, size_t ws_size,
                              hipStream_t stream) {
  const float* X     = (const float*)d_in[0];
  const float* A_hat = (const float*)d_in[1];
  const float* W1    = (const float*)d_in[2];
  const float* b1    = (const float*)d_in[3];
  const float* W2    = (const float*)d_in[4];
  const float* b2    = (const float*)d_in[5];
  const int*   l0    = (const int*)d_in[6];
  const int*   l1    = (const int*)d_in[7];
  float* out = (float*)d_out;

  if (ws_size < (size_t)(20u << 20)) return;
  char* ws = (char*)d_ws;
  unsigned short* HextT = (unsigned short*)(ws);                      // [256][16384] 8MB
  unsigned short* PextT = (unsigned short*)(ws + (8  << 20));         // [64][16384]  2MB
  float* G1 = (float*)(ws + (10 << 20));                              // [S][256] 4MB (probe scratch after scatter1)
  float* G2 = (float*)(ws + (14 << 20));                              // [S][256] 4MB
  float* G3 = (float*)(ws + (18 << 20));                              // [S][64]  1MB
  unsigned short* W1t = (unsigned short*)(ws + (19 << 20));           // [256][512]
  unsigned short* W2t = (unsigned short*)(ws + (19 << 20) + (256 << 10)); // [64][256]

  hipMemsetAsync(ws,  0, (size_t)(19u << 20), stream);
  hipMemsetAsync(out, 0, (size_t)N_NODES * D_OUT * 4, stream);

  conv_w_t<<<512, 256, 0, stream>>>(W1, W2, W1t, W2t);

  // L0 feature: G1 = X[l0] @ W1          M=4096 K=512 N=256
  gemm_tn<64, 256, 64, false><<<(S_SAMP / 64) * 4, 256, 0, stream>>>(
      X, D_IN, l0, W1t, D_IN, G1, D_HID, D_IN, 4, 1.0f);
  ep_scatter_t<<<(S_SAMP * D_HID + 255) / 256, 256, 0, stream>>>(
      G1, b1, l0, HextT, D_HID, S_SAMP * D_HID);

  // L0 agg: G2 = 4 * A_hat[l1, :] @ Hext  M=4096 K=16384 N=256
  gemm_tn<64, 256, 64, false><<<(S_SAMP / 64) * 8, 256, 0, stream>>>(
      A_hat, N_NODES, l1, HextT, N_NODES, G2, D_HID, N_NODES, 8, 4.0f);

  // L1 feature: G3 = relu(G2) @ W2        M=4096 K=256 N=64
  gemm_tn<64, 64, 64, true><<<(S_SAMP / 64) * 4, 256, 0, stream>>>(
      G2, D_HID, nullptr, W2t, D_HID, G3, D_OUT, D_HID, 4, 1.0f);
  ep_scatter_t<<<(S_SAMP * D_OUT + 255) / 256, 256, 0, stream>>>(
      G3, b2, l1, PextT, D_OUT, S_SAMP * D_OUT);

  // L1 agg: out = 4 * A_hat @ Pext        M=16384 K=16384 N=64
  gemm_tn<64, 64, 64, false><<<(N_NODES / 64) * 8, 256, 0, stream>>>(
      A_hat, N_NODES, nullptr, PextT, N_NODES, out, D_OUT, N_NODES, 8, 4.0f);

  // ---- diagnostic probes (dead scratch output; after real chain) ----
  // probe of gemm4, 4 reps -> one ~800us dispatch with PMC
  gemm_probe<64, 64, 64><<<(N_NODES / 64) * 8, 256, 0, stream>>>(
      A_hat, N_NODES, nullptr, PextT, N_NODES, G1, D_OUT, N_NODES, 8, 4.0f, 4);
  // probe of gemm2, 10 reps -> one ~850us dispatch with PMC
  gemm_probe<64, 256, 64><<<(S_SAMP / 64) * 8, 256, 0, stream>>>(
      A_hat, N_NODES, l1, HextT, N_NODES, G1, D_HID, N_NODES, 8, 4.0f, 10);
}

// Round 10
// 527.068 us; speedup vs baseline: 3.5510x; 3.5510x over previous
//
#include <hip/hip_runtime.h>
#include <hip/hip_bf16.h>
#include <stdint.h>

typedef __attribute__((ext_vector_type(8))) short short8;
typedef __attribute__((ext_vector_type(4))) float f32x4;

#define N_NODES 16384
#define D_IN    512
#define D_HID   256
#define D_OUT   64
#define S_SAMP  4096

__device__ __forceinline__ unsigned short f2bf(float f) {
  __hip_bfloat16 h = __float2bfloat16(f);
  union { __hip_bfloat16 h; unsigned short u; } cv; cv.h = h; return cv.u;
}

// ---------------------------------------------------------------------------
// gemm_tn — R2 baseline (single-buffered As/Bs, BK=64, two barriers/K-step).
// Used for gemm1 / gemm2 / gemm3.
// ---------------------------------------------------------------------------
template<int BM, int BN, int BK, bool RELU_A>
__global__ __launch_bounds__(256)
void gemm_tn(const float* __restrict__ A, int lda,
             const int* __restrict__ arow,
             const unsigned short* __restrict__ Bt, int ldb,
             float* __restrict__ C, int ldc,
             int K, int kChunks, float scale)
{
  static_assert(BM == 64 && BK == 64 && (BN == 64 || BN == 256), "tile");
  constexpr int CH    = BK / 8;
  constexpr int RPS   = 512 / BK;
  constexpr int SLABS = BN / RPS;
  constexpr int SLABW = SLABS / 4;

  const int mt  = blockIdx.x / kChunks;
  const int kc  = blockIdx.x % kChunks;
  const int kLen = K / kChunks;
  const int k0   = kc * kLen;
  const int tid  = threadIdx.x;
  const int lane = tid & 63;
  const int wid  = tid >> 6;
  const int l16  = lane & 15;
  const int lg   = lane >> 4;

  __shared__ unsigned short As[BM * BK];
  __shared__ unsigned short Bs[BN * BK];

  constexpr int WN  = (BN == 256) ? 4 : 2;
  constexpr int WM  = 4 / WN;
  constexpr int WTM = BM / WM;
  constexpr int WTN = BN / WN;
  constexpr int MF  = WTM / 16;
  constexpr int NF  = WTN / 16;
  const int wrow = wid / WN;
  const int wcol = wid % WN;

  f32x4 acc[MF][NF] = {};

  const int am   = tid >> 2;
  const int aseg = tid & 3;
  const int arowIdx = mt * BM + am;
  const size_t rowg = arow ? (size_t)arow[arowIdx] : (size_t)arowIdx;
  const float* aBase = A + rowg * (size_t)lda + k0 + aseg * 16;

  const int brow = lane / CH;
  const int bcol = 8 * ((lane % CH) ^ (brow & (CH - 1)));
  const unsigned short* bSrc = Bt + (size_t)brow * ldb + k0 + bcol;

  for (int ks = 0; ks < kLen; ks += BK) {
    __syncthreads();
    #pragma unroll
    for (int i = 0; i < SLABW; ++i) {
      const int s = wid * SLABW + i;
      __builtin_amdgcn_global_load_lds(
          (const __attribute__((address_space(1))) uint32_t*)(bSrc + (size_t)s * RPS * ldb + ks),
          (__attribute__((address_space(3))) uint32_t*)(&Bs[s * 512]),
          16, 0, 0);
    }
    {
      const float* ap = aBase + ks;
      f32x4 v0 = *(const f32x4*)(ap + 0);
      f32x4 v1 = *(const f32x4*)(ap + 4);
      f32x4 v2 = *(const f32x4*)(ap + 8);
      f32x4 v3 = *(const f32x4*)(ap + 12);
      if (RELU_A) {
        #pragma unroll
        for (int j = 0; j < 4; ++j) {
          v0[j] = fmaxf(v0[j], 0.f); v1[j] = fmaxf(v1[j], 0.f);
          v2[j] = fmaxf(v2[j], 0.f); v3[j] = fmaxf(v3[j], 0.f);
        }
      }
      short8 s0, s1;
      s0[0]=f2bf(v0[0]); s0[1]=f2bf(v0[1]); s0[2]=f2bf(v0[2]); s0[3]=f2bf(v0[3]);
      s0[4]=f2bf(v1[0]); s0[5]=f2bf(v1[1]); s0[6]=f2bf(v1[2]); s0[7]=f2bf(v1[3]);
      s1[0]=f2bf(v2[0]); s1[1]=f2bf(v2[1]); s1[2]=f2bf(v2[2]); s1[3]=f2bf(v2[3]);
      s1[4]=f2bf(v3[0]); s1[5]=f2bf(v3[1]); s1[6]=f2bf(v3[2]); s1[7]=f2bf(v3[3]);
      const int g0 = (aseg * 2)     ^ (am & 7);
      const int g1 = (aseg * 2 + 1) ^ (am & 7);
      *(short8*)&As[am * BK + g0 * 8] = s0;
      *(short8*)&As[am * BK + g1 * 8] = s1;
    }
    __syncthreads();
    #pragma unroll
    for (int kk = 0; kk < BK / 32; ++kk) {
      const int gk = kk * 4 + lg;
      short8 af[MF], bfr[NF];
      #pragma unroll
      for (int fm = 0; fm < MF; ++fm) {
        const int m = wrow * WTM + fm * 16 + l16;
        af[fm] = *(const short8*)&As[m * BK + ((gk ^ (m & 7)) * 8)];
      }
      #pragma unroll
      for (int fn = 0; fn < NF; ++fn) {
        const int n = wcol * WTN + fn * 16 + l16;
        bfr[fn] = *(const short8*)&Bs[n * BK + ((gk ^ (n & 7)) * 8)];
      }
      #pragma unroll
      for (int fm = 0; fm < MF; ++fm)
        #pragma unroll
        for (int fn = 0; fn < NF; ++fn)
          acc[fm][fn] = __builtin_amdgcn_mfma_f32_16x16x32_bf16(
              af[fm], bfr[fn], acc[fm][fn], 0, 0, 0);
    }
  }
  #pragma unroll
  for (int fm = 0; fm < MF; ++fm)
    #pragma unroll
    for (int fn = 0; fn < NF; ++fn)
      #pragma unroll
      for (int j = 0; j < 4; ++j) {
        const int r = mt * BM + wrow * WTM + fm * 16 + lg * 4 + j;
        const int c = wcol * WTN + fn * 16 + l16;
        atomicAdd(&C[(size_t)r * ldc + c], scale * acc[fm][fn][j]);
      }
}

// ---------------------------------------------------------------------------
// gemm4_direct — L1 agg only (out = 4 * A_hat @ Pext). BN=64, WN=1: wave wid
// owns rows [mt*64+wid*16, +16) x all 64 cols. NO LDS, NO barriers: A and B
// both loaded straight into MFMA fragment registers (A from HBM — 128B/row
// per K-step, fully coalesced; B from L2 — Pext is 2MB, resident per-XCD).
// Waves free-run; latency hidden by 24 waves/CU TLP + compiler pipelining.
// Fragment layouts verified on-HW in R5 (passed validation).
// ---------------------------------------------------------------------------
__global__ __launch_bounds__(256, 6)
void gemm4_direct(const float* __restrict__ A, int lda,
                  const unsigned short* __restrict__ Bt, int ldb,
                  float* __restrict__ C, int ldc,
                  int K, int kChunks, float scale)
{
  const int mt   = blockIdx.x / kChunks;
  const int kc   = blockIdx.x % kChunks;
  const int kLen = K / kChunks;
  const int k0   = kc * kLen;
  const int tid  = threadIdx.x;
  const int lane = tid & 63;
  const int wid  = tid >> 6;
  const int l16  = lane & 15;
  const int lg   = lane >> 4;

  const int row = mt * 64 + wid * 16 + l16;
  const float* aPtr = A + (size_t)row * lda + k0 + lg * 8;
  const unsigned short* bPtr = Bt + (size_t)l16 * ldb + k0 + lg * 8;

  f32x4 acc[4] = {};

  const int nk = kLen / 32;
  #pragma unroll 4
  for (int t = 0; t < nk; ++t) {
    const float* ap = aPtr + t * 32;
    f32x4 a0 = *(const f32x4*)(ap);
    f32x4 a1 = *(const f32x4*)(ap + 4);
    const unsigned short* bp = bPtr + t * 32;
    short8 b0 = *(const short8*)(bp);
    short8 b1 = *(const short8*)(bp + (size_t)16 * ldb);
    short8 b2 = *(const short8*)(bp + (size_t)32 * ldb);
    short8 b3 = *(const short8*)(bp + (size_t)48 * ldb);
    short8 af;
    af[0]=f2bf(a0[0]); af[1]=f2bf(a0[1]); af[2]=f2bf(a0[2]); af[3]=f2bf(a0[3]);
    af[4]=f2bf(a1[0]); af[5]=f2bf(a1[1]); af[6]=f2bf(a1[2]); af[7]=f2bf(a1[3]);
    acc[0] = __builtin_amdgcn_mfma_f32_16x16x32_bf16(af, b0, acc[0], 0, 0, 0);
    acc[1] = __builtin_amdgcn_mfma_f32_16x16x32_bf16(af, b1, acc[1], 0, 0, 0);
    acc[2] = __builtin_amdgcn_mfma_f32_16x16x32_bf16(af, b2, acc[2], 0, 0, 0);
    acc[3] = __builtin_amdgcn_mfma_f32_16x16x32_bf16(af, b3, acc[3], 0, 0, 0);
  }

  // epilogue: scaled f32 atomic add. C/D frag: col=l16, row=lg*4+j.
  #pragma unroll
  for (int fn = 0; fn < 4; ++fn)
    #pragma unroll
    for (int j = 0; j < 4; ++j) {
      const int rr = mt * 64 + wid * 16 + lg * 4 + j;
      const int cc = fn * 16 + l16;
      atomicAdd(&C[(size_t)rr * ldc + cc], scale * acc[fn][j]);
    }
}

// transpose-convert weights: W1t[j][i] = bf16(W1[i][j]), W2t likewise
__global__ void conv_w_t(const float* __restrict__ W1, const float* __restrict__ W2,
                         unsigned short* __restrict__ W1t, unsigned short* __restrict__ W2t) {
  const int idx = blockIdx.x * 256 + threadIdx.x;
  if (idx < D_IN * D_HID) {
    const int j = idx / D_IN, i = idx % D_IN;
    W1t[idx] = f2bf(W1[(size_t)i * D_HID + j]);
  }
  if (idx < D_HID * D_OUT) {
    const int j = idx / D_HID, i = idx % D_HID;
    W2t[idx] = f2bf(W2[(size_t)i * D_OUT + j]);
  }
}

// BextT[c][rows[r]] = bf16(relu(G[r][c] + bias[c]))   (BextT pre-zeroed)
__global__ void ep_scatter_t(const float* __restrict__ G, const float* __restrict__ bias,
                             const int* __restrict__ rows, unsigned short* __restrict__ BextT,
                             int ncol, int total) {
  const int idx = blockIdx.x * 256 + threadIdx.x;
  if (idx >= total) return;
  const int c = idx / S_SAMP;
  const int r = idx & (S_SAMP - 1);
  float v = G[(size_t)r * ncol + c] + bias[c];
  v = v > 0.f ? v : 0.f;
  BextT[(size_t)c * N_NODES + rows[r]] = f2bf(v);
}

extern "C" void kernel_launch(void* const* d_in, const int* in_sizes, int n_in,
                              void* d_out, int out_size, void* d_ws, size_t ws_size,
                              hipStream_t stream) {
  const float* X     = (const float*)d_in[0];
  const float* A_hat = (const float*)d_in[1];
  const float* W1    = (const float*)d_in[2];
  const float* b1    = (const float*)d_in[3];
  const float* W2    = (const float*)d_in[4];
  const float* b2    = (const float*)d_in[5];
  const int*   l0    = (const int*)d_in[6];
  const int*   l1    = (const int*)d_in[7];
  float* out = (float*)d_out;

  if (ws_size < (size_t)(20u << 20)) return;
  char* ws = (char*)d_ws;
  unsigned short* HextT = (unsigned short*)(ws);                      // [256][16384] 8MB
  unsigned short* PextT = (unsigned short*)(ws + (8  << 20));         // [64][16384]  2MB
  float* G1 = (float*)(ws + (10 << 20));                              // [S][256] 4MB
  float* G2 = (float*)(ws + (14 << 20));                              // [S][256] 4MB
  float* G3 = (float*)(ws + (18 << 20));                              // [S][64]  1MB
  unsigned short* W1t = (unsigned short*)(ws + (19 << 20));           // [256][512]
  unsigned short* W2t = (unsigned short*)(ws + (19 << 20) + (256 << 10)); // [64][256]

  hipMemsetAsync(ws,  0, (size_t)(19u << 20), stream);
  hipMemsetAsync(out, 0, (size_t)N_NODES * D_OUT * 4, stream);

  conv_w_t<<<512, 256, 0, stream>>>(W1, W2, W1t, W2t);

  // L0 feature: G1 = X[l0] @ W1          M=4096 K=512 N=256
  gemm_tn<64, 256, 64, false><<<(S_SAMP / 64) * 4, 256, 0, stream>>>(
      X, D_IN, l0, W1t, D_IN, G1, D_HID, D_IN, 4, 1.0f);
  ep_scatter_t<<<(S_SAMP * D_HID + 255) / 256, 256, 0, stream>>>(
      G1, b1, l0, HextT, D_HID, S_SAMP * D_HID);

  // L0 agg: G2 = 4 * A_hat[l1, :] @ Hext  M=4096 K=16384 N=256
  gemm_tn<64, 256, 64, false><<<(S_SAMP / 64) * 8, 256, 0, stream>>>(
      A_hat, N_NODES, l1, HextT, N_NODES, G2, D_HID, N_NODES, 8, 4.0f);

  // L1 feature: G3 = relu(G2) @ W2        M=4096 K=256 N=64
  gemm_tn<64, 64, 64, true><<<(S_SAMP / 64) * 4, 256, 0, stream>>>(
      G2, D_HID, nullptr, W2t, D_HID, G3, D_OUT, D_HID, 4, 1.0f);
  ep_scatter_t<<<(S_SAMP * D_OUT + 255) / 256, 256, 0, stream>>>(
      G3, b2, l1, PextT, D_OUT, S_SAMP * D_OUT);

  // L1 agg: out = 4 * A_hat @ Pext        M=16384 K=16384 N=64
  // (2048 blocks; barrier-free direct-register form)
  gemm4_direct<<<(N_NODES / 64) * 8, 256, 0, stream>>>(
      A_hat, N_NODES, PextT, N_NODES, out, D_OUT, N_NODES, 8, 4.0f);
}